// Round 6
// baseline (323.985 us; speedup 1.0000x reference)
//
#include <hip/hip_runtime.h>

#define NB 4096
#define MM 64
#define DD 256
#define LN_EPS 1e-5f
#define NEG_BIG -1e30f

// ws layout (floats):
//   [0,       512*DD)         wcat : [wt^T ; wh^T]
//   [WS_HW,   +NB*DD)         hW
//   [WS_CTX,  +2*NB*DD)       ctx  (row = side*NB + b)
#define WS_WCAT 0
#define WS_HW   (512 * DD)
#define WS_CTX  (WS_HW + NB * DD)

// ---------------- prep: blocks 0..31 transpose wt/wh, 32..287 bilinear ----------------
__global__ __launch_bounds__(256)
void k_prep(const float* __restrict__ head_left,
            const float* __restrict__ head_right,
            const float* __restrict__ bw,
            const float* __restrict__ wt,
            const float* __restrict__ wh,
            float* __restrict__ wcat,
            float* __restrict__ hW)
{
    __shared__ float smem[64 * 65];
    const int t = threadIdx.x;

    if (blockIdx.x < 32) {
        const int mat   = blockIdx.x >> 4;
        const int tile  = blockIdx.x & 15;
        const int dBase = (tile >> 2) * 64;
        const int kBase = (tile & 3) * 64;
        const float* __restrict__ w = mat ? wh : wt;
        float (*tile_s)[65] = (float(*)[65])smem;
        const int c  = t & 63;
        const int rr = t >> 6;
        #pragma unroll
        for (int r = rr; r < 64; r += 4)
            tile_s[r][c] = w[(dBase + r) * DD + kBase + c];
        __syncthreads();
        #pragma unroll
        for (int kr = rr; kr < 64; kr += 4)
            wcat[(mat * 256 + kBase + kr) * DD + dBase + c] = tile_s[c][kr];
    } else {
        const int blk  = blockIdx.x - 32;     // 256 blocks x 16 rows
        const int lane = t & 63;
        const int w    = t >> 6;
        float (*weak_s)[DD] = (float(*)[DD])smem;
        #pragma unroll
        for (int r = 0; r < 16; ++r) {
            const size_t idx = (size_t)(blk * 16 + r) * DD + t;
            weak_s[r][t] = head_right[idx] - head_left[idx];
        }
        __syncthreads();

        float4 acc[4];
        #pragma unroll
        for (int r = 0; r < 4; ++r) acc[r] = make_float4(0.f, 0.f, 0.f, 0.f);
        for (int k = 0; k < DD; ++k) {
            const float4 w4 = *(const float4*)(bw + k * DD + 4 * lane);
            #pragma unroll
            for (int r = 0; r < 4; ++r) {
                const float x = weak_s[4 * w + r][k];
                acc[r].x += x * w4.x; acc[r].y += x * w4.y;
                acc[r].z += x * w4.z; acc[r].w += x * w4.w;
            }
        }
        #pragma unroll
        for (int r = 0; r < 4; ++r)
            *(float4*)(hW + (size_t)(blk * 16 + 4 * w + r) * DD + 4 * lane) = acc[r];
    }
}

// ---------------- attn: round-2 proven structure, paired-row score loop ----------------
__global__ __launch_bounds__(256)
void k_attn(const float* __restrict__ rel_left,
            const float* __restrict__ tail_left,
            const float* __restrict__ rel_right,
            const float* __restrict__ tail_right,
            const unsigned char* __restrict__ mask_left,
            const unsigned char* __restrict__ mask_right,
            const float* __restrict__ hW,
            float* __restrict__ ctx)
{
    const int b    = blockIdx.x >> 1;
    const int side = blockIdx.x & 1;
    const int t    = threadIdx.x;
    const int lane = t & 63;
    const int w    = t >> 6;

    const float* __restrict__ rel  = side ? rel_right  : rel_left;
    const float* __restrict__ tail = side ? tail_right : tail_left;
    const unsigned char* __restrict__ mask = side ? mask_right : mask_left;

    __shared__ float att_s[MM];
    __shared__ float part_s[4][DD];

    const float4 hw4 = *(const float4*)(hW + (size_t)b * DD + 4 * lane);
    const float* rp = rel  + (size_t)b * MM * DD + 4 * lane;
    const float* tp = tail + (size_t)b * MM * DD + 4 * lane;

    // scores: wave w owns m = w*16..w*16+15, two rows per iteration for MLP
    #pragma unroll 2
    for (int i = 0; i < 16; i += 2) {
        const int m = w * 16 + i;
        const float4 ra = *(const float4*)(rp + (size_t)m * DD);
        const float4 rb = *(const float4*)(rp + (size_t)(m + 1) * DD);
        float pa = hw4.x * ra.x + hw4.y * ra.y + hw4.z * ra.z + hw4.w * ra.w;
        float pb = hw4.x * rb.x + hw4.y * rb.y + hw4.z * rb.z + hw4.w * rb.w;
        #pragma unroll
        for (int off = 32; off >= 1; off >>= 1) {
            pa += __shfl_xor(pa, off, 64);
            pb += __shfl_xor(pb, off, 64);
        }
        if (lane == 0) { att_s[m] = pa; att_s[m + 1] = pb; }
    }
    __syncthreads();

    // masked softmax on wave 0 (lane l owns m = l)
    if (w == 0) {
        const unsigned char v0 = mask_left[lane];
        const bool mask_u8 = (__ballot(((lane & 3) != 0) && (v0 != 0)) != 0ULL);

        float s = att_s[lane];
        const bool msk = mask_u8
            ? (mask[(size_t)b * MM + lane] != 0)
            : (((const int*)(const void*)mask)[(size_t)b * MM + lane] != 0);
        if (msk) s = NEG_BIG;
        float mx = s;
        #pragma unroll
        for (int off = 32; off >= 1; off >>= 1) mx = fmaxf(mx, __shfl_xor(mx, off, 64));
        const float e = __expf(s - mx);
        float sum = e;
        #pragma unroll
        for (int off = 32; off >= 1; off >>= 1) sum += __shfl_xor(sum, off, 64);
        att_s[lane] = e / sum;
    }
    __syncthreads();

    // ctx: wave w streams tail rows w*16..w*16+15
    float4 acc = make_float4(0.f, 0.f, 0.f, 0.f);
    #pragma unroll 4
    for (int i = 0; i < 16; ++i) {
        const int m = w * 16 + i;
        const float a  = att_s[m];
        const float4 v = *(const float4*)(tp + (size_t)m * DD);
        acc.x += a * v.x; acc.y += a * v.y; acc.z += a * v.z; acc.w += a * v.w;
    }
    *(float4*)(&part_s[w][4 * lane]) = acc;
    __syncthreads();

    const float sum = part_s[0][t] + part_s[1][t] + part_s[2][t] + part_s[3][t];
    ctx[(size_t)(side * NB + b) * DD + t] = sum;
}

// ---------------- E: out = LN(relu([ctx|head] @ wcat) + head) ----------------
// 256 blocks x 32 rows; 4 waves x 8 rows/wave -> wcat L1 traffic 536 MB total.
__global__ __launch_bounds__(256)
void k_outln(const float* __restrict__ ctx,
             const float* __restrict__ head_left,
             const float* __restrict__ head_right,
             const float* __restrict__ wcat,
             const float* __restrict__ gamma,
             const float* __restrict__ beta,
             float* __restrict__ out)
{
    const int blk  = blockIdx.x;           // 256 blocks x 32 rows
    const int t    = threadIdx.x;          // 256 threads, 4 waves
    const int lane = t & 63;
    const int w    = t >> 6;

    __shared__ float x_s[32][512];         // 64 KB: [r][0:256)=ctx, [256:512)=head_side

    const int  side = (blk * 32) >> 12;    // uniform per block (128 blocks per side)
    const float* __restrict__ head = side ? head_right : head_left;

    // cooperative load: 32*512 floats / 256 threads = 64 each, coalesced
    #pragma unroll
    for (int i = 0; i < 64; ++i) {
        const int idx = i * 256 + t;
        const int r   = idx >> 9;
        const int c   = idx & 511;
        const int rg  = blk * 32 + r;
        const int bb  = rg & (NB - 1);
        x_s[r][c] = (c < DD) ? ctx[(size_t)rg * DD + c]
                             : head[(size_t)bb * DD + (c - DD)];
    }
    __syncthreads();

    float4 acc[8];
    #pragma unroll
    for (int r = 0; r < 8; ++r) acc[r] = make_float4(0.f, 0.f, 0.f, 0.f);

    #pragma unroll 4
    for (int k = 0; k < 512; ++k) {
        const float4 w4 = *(const float4*)(wcat + (size_t)k * DD + 4 * lane);
        #pragma unroll
        for (int r = 0; r < 8; ++r) {
            const float x = x_s[8 * w + r][k];
            acc[r].x += x * w4.x; acc[r].y += x * w4.y;
            acc[r].z += x * w4.z; acc[r].w += x * w4.w;
        }
    }

    const float4 g4 = *(const float4*)(gamma + 4 * lane);
    const float4 b4 = *(const float4*)(beta  + 4 * lane);

    #pragma unroll
    for (int r = 0; r < 8; ++r) {
        const int rl = 8 * w + r;
        const float4 h4 = *(const float4*)(&x_s[rl][DD + 4 * lane]);
        float4 y;
        y.x = fmaxf(acc[r].x, 0.f) + h4.x;
        y.y = fmaxf(acc[r].y, 0.f) + h4.y;
        y.z = fmaxf(acc[r].z, 0.f) + h4.z;
        y.w = fmaxf(acc[r].w, 0.f) + h4.w;

        float s1 = y.x + y.y + y.z + y.w;
        float s2 = y.x * y.x + y.y * y.y + y.z * y.z + y.w * y.w;
        #pragma unroll
        for (int off = 32; off >= 1; off >>= 1) {
            s1 += __shfl_xor(s1, off, 64);
            s2 += __shfl_xor(s2, off, 64);
        }
        const float mu   = s1 * (1.0f / DD);
        const float var  = s2 * (1.0f / DD) - mu * mu;
        const float rstd = rsqrtf(var + LN_EPS);

        float4 o;
        o.x = (y.x - mu) * rstd * g4.x + b4.x;
        o.y = (y.y - mu) * rstd * g4.y + b4.y;
        o.z = (y.z - mu) * rstd * g4.z + b4.z;
        o.w = (y.w - mu) * rstd * g4.w + b4.w;
        *(float4*)(out + (size_t)(blk * 32 + rl) * DD + 4 * lane) = o;
    }
}

extern "C" void kernel_launch(void* const* d_in, const int* in_sizes, int n_in,
                              void* d_out, int out_size, void* d_ws, size_t ws_size,
                              hipStream_t stream) {
    const float* head_left  = (const float*)d_in[0];
    const float* rel_left   = (const float*)d_in[1];
    const float* tail_left  = (const float*)d_in[2];
    const float* head_right = (const float*)d_in[3];
    const float* rel_right  = (const float*)d_in[4];
    const float* tail_right = (const float*)d_in[5];
    const unsigned char* mask_left  = (const unsigned char*)d_in[6];
    const unsigned char* mask_right = (const unsigned char*)d_in[7];
    const float* bw    = (const float*)d_in[8];
    const float* wt    = (const float*)d_in[9];
    const float* wh    = (const float*)d_in[10];
    const float* gamma = (const float*)d_in[11];
    const float* beta  = (const float*)d_in[12];
    float* out = (float*)d_out;

    float* ws   = (float*)d_ws;
    float* wcat = ws + WS_WCAT;
    float* hW   = ws + WS_HW;
    float* ctxb = ws + WS_CTX;

    k_prep <<<dim3(288),  dim3(256), 0, stream>>>(head_left, head_right, bw, wt, wh, wcat, hW);
    k_attn <<<dim3(8192), dim3(256), 0, stream>>>(rel_left, tail_left, rel_right, tail_right,
                                                  mask_left, mask_right, hW, ctxb);
    k_outln<<<dim3(256),  dim3(256), 0, stream>>>(ctxb, head_left, head_right, wcat,
                                                  gamma, beta, out);
}

// Round 7
// 303.878 us; speedup vs baseline: 1.0662x; 1.0662x over previous
//
#include <hip/hip_runtime.h>

#define NB 4096
#define MM 64
#define DD 256
#define LN_EPS 1e-5f
#define NEG_BIG -1e30f

// ws layout (floats):
//   [0,       512*DD)         wcat : [wt^T ; wh^T]
//   [WS_HW,   +NB*DD)         hW
//   [WS_CTX,  +2*NB*DD)       ctx  (row = side*NB + b)
#define WS_WCAT 0
#define WS_HW   (512 * DD)
#define WS_CTX  (WS_HW + NB * DD)

// ---------------- prep: blocks 0..31 transpose wt/wh, 32..287 bilinear ----------------
__global__ __launch_bounds__(256)
void k_prep(const float* __restrict__ head_left,
            const float* __restrict__ head_right,
            const float* __restrict__ bw,
            const float* __restrict__ wt,
            const float* __restrict__ wh,
            float* __restrict__ wcat,
            float* __restrict__ hW)
{
    __shared__ float smem[64 * 65];
    const int t = threadIdx.x;

    if (blockIdx.x < 32) {
        const int mat   = blockIdx.x >> 4;
        const int tile  = blockIdx.x & 15;
        const int dBase = (tile >> 2) * 64;
        const int kBase = (tile & 3) * 64;
        const float* __restrict__ w = mat ? wh : wt;
        float (*tile_s)[65] = (float(*)[65])smem;
        const int c  = t & 63;
        const int rr = t >> 6;
        #pragma unroll
        for (int r = rr; r < 64; r += 4)
            tile_s[r][c] = w[(dBase + r) * DD + kBase + c];
        __syncthreads();
        #pragma unroll
        for (int kr = rr; kr < 64; kr += 4)
            wcat[(mat * 256 + kBase + kr) * DD + dBase + c] = tile_s[c][kr];
    } else {
        const int blk  = blockIdx.x - 32;     // 256 blocks x 16 rows
        const int lane = t & 63;
        const int w    = t >> 6;
        float (*weak_s)[DD] = (float(*)[DD])smem;
        #pragma unroll
        for (int r = 0; r < 16; ++r) {
            const size_t idx = (size_t)(blk * 16 + r) * DD + t;
            weak_s[r][t] = head_right[idx] - head_left[idx];
        }
        __syncthreads();

        float4 acc[4];
        #pragma unroll
        for (int r = 0; r < 4; ++r) acc[r] = make_float4(0.f, 0.f, 0.f, 0.f);
        for (int k = 0; k < DD; ++k) {
            const float4 w4 = *(const float4*)(bw + k * DD + 4 * lane);
            #pragma unroll
            for (int r = 0; r < 4; ++r) {
                const float x = weak_s[4 * w + r][k];
                acc[r].x += x * w4.x; acc[r].y += x * w4.y;
                acc[r].z += x * w4.z; acc[r].w += x * w4.w;
            }
        }
        #pragma unroll
        for (int r = 0; r < 4; ++r)
            *(float4*)(hW + (size_t)(blk * 16 + 4 * w + r) * DD + 4 * lane) = acc[r];
    }
}

// ---------------- attn: shfl-free score stream -> LDS reduce -> softmax -> tail stream ----------------
__global__ __launch_bounds__(256)
void k_attn(const float* __restrict__ rel_left,
            const float* __restrict__ tail_left,
            const float* __restrict__ rel_right,
            const float* __restrict__ tail_right,
            const unsigned char* __restrict__ mask_left,
            const unsigned char* __restrict__ mask_right,
            const float* __restrict__ hW,
            float* __restrict__ ctx)
{
    const int b    = blockIdx.x >> 1;
    const int side = blockIdx.x & 1;
    const int t    = threadIdx.x;
    const int lane = t & 63;
    const int w    = t >> 6;

    const float* __restrict__ rel  = side ? rel_right  : rel_left;
    const float* __restrict__ tail = side ? tail_right : tail_left;
    const unsigned char* __restrict__ mask = side ? mask_right : mask_left;

    __shared__ float part_s[MM][65];   // +1 pad: conflict-free write (by lane) AND read (by m)
    __shared__ float red_s[MM][5];
    __shared__ float att_s[MM];
    __shared__ float cpart_s[4][DD];

    const float4 hw4 = *(const float4*)(hW + (size_t)b * DD + 4 * lane);
    const float* rp = rel  + (size_t)b * MM * DD + 4 * lane;
    const float* tp = tail + (size_t)b * MM * DD + 4 * lane;

    // ---- phase 1: pure rel stream; per-lane partial -> LDS; NO cross-lane ops ----
    #pragma unroll
    for (int i = 0; i < 16; ++i) {
        const int m = w * 16 + i;
        const float4 r4 = *(const float4*)(rp + (size_t)m * DD);
        part_s[m][lane] = hw4.x * r4.x + hw4.y * r4.y + hw4.z * r4.z + hw4.w * r4.w;
    }
    __syncthreads();

    // ---- phase 2: batched reduce. thread t: row m=t&63, chunk c=t>>6 sums 16 values ----
    {
        const int m = t & 63;
        const int c = t >> 6;
        float s = 0.f;
        #pragma unroll
        for (int j = 0; j < 16; ++j) s += part_s[m][c * 16 + j];
        red_s[m][c] = s;
    }
    __syncthreads();

    // ---- softmax on wave 0 (lane = m) ----
    if (w == 0) {
        const unsigned char v0 = mask_left[lane];
        const bool mask_u8 = (__ballot(((lane & 3) != 0) && (v0 != 0)) != 0ULL);

        float s = red_s[lane][0] + red_s[lane][1] + red_s[lane][2] + red_s[lane][3];
        const bool msk = mask_u8
            ? (mask[(size_t)b * MM + lane] != 0)
            : (((const int*)(const void*)mask)[(size_t)b * MM + lane] != 0);
        if (msk) s = NEG_BIG;
        float mx = s;
        #pragma unroll
        for (int off = 32; off >= 1; off >>= 1) mx = fmaxf(mx, __shfl_xor(mx, off, 64));
        const float e = __expf(s - mx);
        float sum = e;
        #pragma unroll
        for (int off = 32; off >= 1; off >>= 1) sum += __shfl_xor(sum, off, 64);
        att_s[lane] = e / sum;
    }
    __syncthreads();

    // ---- phase 3: pure tail stream with broadcast att ----
    float4 acc = make_float4(0.f, 0.f, 0.f, 0.f);
    #pragma unroll 4
    for (int i = 0; i < 16; ++i) {
        const int m = w * 16 + i;
        const float a  = att_s[m];
        const float4 v = *(const float4*)(tp + (size_t)m * DD);
        acc.x += a * v.x; acc.y += a * v.y; acc.z += a * v.z; acc.w += a * v.w;
    }
    *(float4*)(&cpart_s[w][4 * lane]) = acc;
    __syncthreads();

    const float sum = cpart_s[0][t] + cpart_s[1][t] + cpart_s[2][t] + cpart_s[3][t];
    ctx[(size_t)(side * NB + b) * DD + t] = sum;
}

// ---------------- E (round-4 proven): 512 blocks x 16 rows, 512 threads ----------------
__global__ __launch_bounds__(512)
void k_outln(const float* __restrict__ ctx,
             const float* __restrict__ head_left,
             const float* __restrict__ head_right,
             const float* __restrict__ wcat,
             const float* __restrict__ gamma,
             const float* __restrict__ beta,
             float* __restrict__ out)
{
    const int blk  = blockIdx.x;           // 512 blocks x 16 rows
    const int t    = threadIdx.x;          // 512 threads, 8 waves
    const int lane = t & 63;
    const int w    = t >> 6;

    __shared__ float x_s[16][512];

    const int  side = (blk * 16) >> 12;
    const float* __restrict__ head = side ? head_right : head_left;

    #pragma unroll
    for (int i = 0; i < 16; ++i) {
        const int idx = i * 512 + t;
        const int r   = idx >> 9;
        const int c   = idx & 511;
        const int rg  = blk * 16 + r;
        const int bb  = rg & (NB - 1);
        x_s[r][c] = (c < DD) ? ctx[(size_t)rg * DD + c]
                             : head[(size_t)bb * DD + (c - DD)];
    }
    __syncthreads();

    float4 acc[2];
    acc[0] = make_float4(0.f, 0.f, 0.f, 0.f);
    acc[1] = make_float4(0.f, 0.f, 0.f, 0.f);

    #pragma unroll 4
    for (int k = 0; k < 512; ++k) {
        const float4 w4 = *(const float4*)(wcat + (size_t)k * DD + 4 * lane);
        #pragma unroll
        for (int r = 0; r < 2; ++r) {
            const float x = x_s[2 * w + r][k];
            acc[r].x += x * w4.x; acc[r].y += x * w4.y;
            acc[r].z += x * w4.z; acc[r].w += x * w4.w;
        }
    }

    const float4 g4 = *(const float4*)(gamma + 4 * lane);
    const float4 b4 = *(const float4*)(beta  + 4 * lane);

    #pragma unroll
    for (int r = 0; r < 2; ++r) {
        const int rl = 2 * w + r;
        const float4 h4 = *(const float4*)(&x_s[rl][DD + 4 * lane]);
        float4 y;
        y.x = fmaxf(acc[r].x, 0.f) + h4.x;
        y.y = fmaxf(acc[r].y, 0.f) + h4.y;
        y.z = fmaxf(acc[r].z, 0.f) + h4.z;
        y.w = fmaxf(acc[r].w, 0.f) + h4.w;

        float s1 = y.x + y.y + y.z + y.w;
        float s2 = y.x * y.x + y.y * y.y + y.z * y.z + y.w * y.w;
        #pragma unroll
        for (int off = 32; off >= 1; off >>= 1) {
            s1 += __shfl_xor(s1, off, 64);
            s2 += __shfl_xor(s2, off, 64);
        }
        const float mu   = s1 * (1.0f / DD);
        const float var  = s2 * (1.0f / DD) - mu * mu;
        const float rstd = rsqrtf(var + LN_EPS);

        float4 o;
        o.x = (y.x - mu) * rstd * g4.x + b4.x;
        o.y = (y.y - mu) * rstd * g4.y + b4.y;
        o.z = (y.z - mu) * rstd * g4.z + b4.z;
        o.w = (y.w - mu) * rstd * g4.w + b4.w;
        *(float4*)(out + (size_t)(blk * 16 + rl) * DD + 4 * lane) = o;
    }
}

extern "C" void kernel_launch(void* const* d_in, const int* in_sizes, int n_in,
                              void* d_out, int out_size, void* d_ws, size_t ws_size,
                              hipStream_t stream) {
    const float* head_left  = (const float*)d_in[0];
    const float* rel_left   = (const float*)d_in[1];
    const float* tail_left  = (const float*)d_in[2];
    const float* head_right = (const float*)d_in[3];
    const float* rel_right  = (const float*)d_in[4];
    const float* tail_right = (const float*)d_in[5];
    const unsigned char* mask_left  = (const unsigned char*)d_in[6];
    const unsigned char* mask_right = (const unsigned char*)d_in[7];
    const float* bw    = (const float*)d_in[8];
    const float* wt    = (const float*)d_in[9];
    const float* wh    = (const float*)d_in[10];
    const float* gamma = (const float*)d_in[11];
    const float* beta  = (const float*)d_in[12];
    float* out = (float*)d_out;

    float* ws   = (float*)d_ws;
    float* wcat = ws + WS_WCAT;
    float* hW   = ws + WS_HW;
    float* ctxb = ws + WS_CTX;

    k_prep <<<dim3(288),  dim3(256), 0, stream>>>(head_left, head_right, bw, wt, wh, wcat, hW);
    k_attn <<<dim3(8192), dim3(256), 0, stream>>>(rel_left, tail_left, rel_right, tail_right,
                                                  mask_left, mask_right, hW, ctxb);
    k_outln<<<dim3(512),  dim3(512), 0, stream>>>(ctxb, head_left, head_right, wcat,
                                                  gamma, beta, out);
}

// Round 8
// 249.834 us; speedup vs baseline: 1.2968x; 1.2163x over previous
//
#include <hip/hip_runtime.h>

#define NB 4096
#define MM 64
#define DD 256
#define LN_EPS 1e-5f
#define NEG_BIG -1e30f

typedef float f4v __attribute__((ext_vector_type(4)));

// ws layout (floats):
//   [0,       512*DD)         wcat : [wt^T ; wh^T]
//   [WS_HW,   +NB*DD)         hW
//   [WS_CTX,  +2*NB*DD)       ctx  (row = side*NB + b)
#define WS_WCAT 0
#define WS_HW   (512 * DD)
#define WS_CTX  (WS_HW + NB * DD)

// ---------------- prep: blocks 0..31 transpose wt/wh, 32..287 bilinear ----------------
__global__ __launch_bounds__(256)
void k_prep(const float* __restrict__ head_left,
            const float* __restrict__ head_right,
            const float* __restrict__ bw,
            const float* __restrict__ wt,
            const float* __restrict__ wh,
            float* __restrict__ wcat,
            float* __restrict__ hW)
{
    __shared__ float smem[64 * 65];
    const int t = threadIdx.x;

    if (blockIdx.x < 32) {
        const int mat   = blockIdx.x >> 4;
        const int tile  = blockIdx.x & 15;
        const int dBase = (tile >> 2) * 64;
        const int kBase = (tile & 3) * 64;
        const float* __restrict__ w = mat ? wh : wt;
        float (*tile_s)[65] = (float(*)[65])smem;
        const int c  = t & 63;
        const int rr = t >> 6;
        #pragma unroll
        for (int r = rr; r < 64; r += 4)
            tile_s[r][c] = w[(dBase + r) * DD + kBase + c];
        __syncthreads();
        #pragma unroll
        for (int kr = rr; kr < 64; kr += 4)
            wcat[(mat * 256 + kBase + kr) * DD + dBase + c] = tile_s[c][kr];
    } else {
        const int blk  = blockIdx.x - 32;     // 256 blocks x 16 rows
        const int lane = t & 63;
        const int w    = t >> 6;
        float (*weak_s)[DD] = (float(*)[DD])smem;
        #pragma unroll
        for (int r = 0; r < 16; ++r) {
            const size_t idx = (size_t)(blk * 16 + r) * DD + t;
            weak_s[r][t] = head_right[idx] - head_left[idx];
        }
        __syncthreads();

        float4 acc[4];
        #pragma unroll
        for (int r = 0; r < 4; ++r) acc[r] = make_float4(0.f, 0.f, 0.f, 0.f);
        for (int k = 0; k < DD; ++k) {
            const float4 w4 = *(const float4*)(bw + k * DD + 4 * lane);
            #pragma unroll
            for (int r = 0; r < 4; ++r) {
                const float x = weak_s[4 * w + r][k];
                acc[r].x += x * w4.x; acc[r].y += x * w4.y;
                acc[r].z += x * w4.z; acc[r].w += x * w4.w;
            }
        }
        #pragma unroll
        for (int r = 0; r < 4; ++r)
            *(float4*)(hW + (size_t)(blk * 16 + 4 * w + r) * DD + 4 * lane) = acc[r];
    }
}

// ---------------- attn: shfl-free score stream -> LDS reduce -> softmax -> tail stream ----------------
// rel/tail loads are nontemporal (read-exactly-once streams).
__global__ __launch_bounds__(256)
void k_attn(const float* __restrict__ rel_left,
            const float* __restrict__ tail_left,
            const float* __restrict__ rel_right,
            const float* __restrict__ tail_right,
            const unsigned char* __restrict__ mask_left,
            const unsigned char* __restrict__ mask_right,
            const float* __restrict__ hW,
            float* __restrict__ ctx)
{
    const int b    = blockIdx.x >> 1;
    const int side = blockIdx.x & 1;
    const int t    = threadIdx.x;
    const int lane = t & 63;
    const int w    = t >> 6;

    const float* __restrict__ rel  = side ? rel_right  : rel_left;
    const float* __restrict__ tail = side ? tail_right : tail_left;
    const unsigned char* __restrict__ mask = side ? mask_right : mask_left;

    __shared__ float part_s[MM][65];   // +1 pad: conflict-free write (by lane) AND read (by m)
    __shared__ float red_s[MM][5];
    __shared__ float att_s[MM];
    __shared__ float cpart_s[4][DD];

    const float4 hw4 = *(const float4*)(hW + (size_t)b * DD + 4 * lane);
    const float* rp = rel  + (size_t)b * MM * DD + 4 * lane;
    const float* tp = tail + (size_t)b * MM * DD + 4 * lane;

    // ---- phase 1: pure rel stream; per-lane partial -> LDS; NO cross-lane ops ----
    #pragma unroll
    for (int i = 0; i < 16; ++i) {
        const int m = w * 16 + i;
        const f4v r4 = __builtin_nontemporal_load((const f4v*)(rp + (size_t)m * DD));
        part_s[m][lane] = hw4.x * r4.x + hw4.y * r4.y + hw4.z * r4.z + hw4.w * r4.w;
    }
    __syncthreads();

    // ---- phase 2: batched reduce. thread t: row m=t&63, chunk c=t>>6 sums 16 values ----
    {
        const int m = t & 63;
        const int c = t >> 6;
        float s = 0.f;
        #pragma unroll
        for (int j = 0; j < 16; ++j) s += part_s[m][c * 16 + j];
        red_s[m][c] = s;
    }
    __syncthreads();

    // ---- softmax on wave 0 (lane = m) ----
    if (w == 0) {
        const unsigned char v0 = mask_left[lane];
        const bool mask_u8 = (__ballot(((lane & 3) != 0) && (v0 != 0)) != 0ULL);

        float s = red_s[lane][0] + red_s[lane][1] + red_s[lane][2] + red_s[lane][3];
        const bool msk = mask_u8
            ? (mask[(size_t)b * MM + lane] != 0)
            : (((const int*)(const void*)mask)[(size_t)b * MM + lane] != 0);
        if (msk) s = NEG_BIG;
        float mx = s;
        #pragma unroll
        for (int off = 32; off >= 1; off >>= 1) mx = fmaxf(mx, __shfl_xor(mx, off, 64));
        const float e = __expf(s - mx);
        float sum = e;
        #pragma unroll
        for (int off = 32; off >= 1; off >>= 1) sum += __shfl_xor(sum, off, 64);
        att_s[lane] = e / sum;
    }
    __syncthreads();

    // ---- phase 3: pure tail stream with broadcast att ----
    float4 acc = make_float4(0.f, 0.f, 0.f, 0.f);
    #pragma unroll 4
    for (int i = 0; i < 16; ++i) {
        const int m = w * 16 + i;
        const float a  = att_s[m];
        const f4v v = __builtin_nontemporal_load((const f4v*)(tp + (size_t)m * DD));
        acc.x += a * v.x; acc.y += a * v.y; acc.z += a * v.z; acc.w += a * v.w;
    }
    *(float4*)(&cpart_s[w][4 * lane]) = acc;
    __syncthreads();

    const float sum = cpart_s[0][t] + cpart_s[1][t] + cpart_s[2][t] + cpart_s[3][t];
    ctx[(size_t)(side * NB + b) * DD + t] = sum;
}

// ---------------- E: 512 blocks x 16 rows, 256 threads, 4 rows/wave ----------------
// wcat L1 traffic = 2048 waves x 512 KB = 1 GB (halved vs r=2 config).
__global__ __launch_bounds__(256)
void k_outln(const float* __restrict__ ctx,
             const float* __restrict__ head_left,
             const float* __restrict__ head_right,
             const float* __restrict__ wcat,
             const float* __restrict__ gamma,
             const float* __restrict__ beta,
             float* __restrict__ out)
{
    const int blk  = blockIdx.x;           // 512 blocks x 16 rows
    const int t    = threadIdx.x;          // 256 threads, 4 waves
    const int lane = t & 63;
    const int w    = t >> 6;

    __shared__ float x_s[16][512];         // 32 KB

    const int  side = (blk * 16) >> 12;
    const float* __restrict__ head = side ? head_right : head_left;

    // cooperative load: 16*512 floats / 256 threads = 32 each, coalesced
    #pragma unroll
    for (int i = 0; i < 32; ++i) {
        const int idx = i * 256 + t;
        const int r   = idx >> 9;
        const int c   = idx & 511;
        const int rg  = blk * 16 + r;
        const int bb  = rg & (NB - 1);
        x_s[r][c] = (c < DD) ? ctx[(size_t)rg * DD + c]
                             : head[(size_t)bb * DD + (c - DD)];
    }
    __syncthreads();

    float4 acc[4];
    #pragma unroll
    for (int r = 0; r < 4; ++r) acc[r] = make_float4(0.f, 0.f, 0.f, 0.f);

    #pragma unroll 4
    for (int k = 0; k < 512; ++k) {
        const float4 w4 = *(const float4*)(wcat + (size_t)k * DD + 4 * lane);
        #pragma unroll
        for (int r = 0; r < 4; ++r) {
            const float x = x_s[4 * w + r][k];
            acc[r].x += x * w4.x; acc[r].y += x * w4.y;
            acc[r].z += x * w4.z; acc[r].w += x * w4.w;
        }
    }

    const float4 g4 = *(const float4*)(gamma + 4 * lane);
    const float4 b4 = *(const float4*)(beta  + 4 * lane);

    #pragma unroll
    for (int r = 0; r < 4; ++r) {
        const int rl = 4 * w + r;
        const float4 h4 = *(const float4*)(&x_s[rl][DD + 4 * lane]);
        float4 y;
        y.x = fmaxf(acc[r].x, 0.f) + h4.x;
        y.y = fmaxf(acc[r].y, 0.f) + h4.y;
        y.z = fmaxf(acc[r].z, 0.f) + h4.z;
        y.w = fmaxf(acc[r].w, 0.f) + h4.w;

        float s1 = y.x + y.y + y.z + y.w;
        float s2 = y.x * y.x + y.y * y.y + y.z * y.z + y.w * y.w;
        #pragma unroll
        for (int off = 32; off >= 1; off >>= 1) {
            s1 += __shfl_xor(s1, off, 64);
            s2 += __shfl_xor(s2, off, 64);
        }
        const float mu   = s1 * (1.0f / DD);
        const float var  = s2 * (1.0f / DD) - mu * mu;
        const float rstd = rsqrtf(var + LN_EPS);

        float4 o;
        o.x = (y.x - mu) * rstd * g4.x + b4.x;
        o.y = (y.y - mu) * rstd * g4.y + b4.y;
        o.z = (y.z - mu) * rstd * g4.z + b4.z;
        o.w = (y.w - mu) * rstd * g4.w + b4.w;
        *(float4*)(out + (size_t)(blk * 16 + rl) * DD + 4 * lane) = o;
    }
}

extern "C" void kernel_launch(void* const* d_in, const int* in_sizes, int n_in,
                              void* d_out, int out_size, void* d_ws, size_t ws_size,
                              hipStream_t stream) {
    const float* head_left  = (const float*)d_in[0];
    const float* rel_left   = (const float*)d_in[1];
    const float* tail_left  = (const float*)d_in[2];
    const float* head_right = (const float*)d_in[3];
    const float* rel_right  = (const float*)d_in[4];
    const float* tail_right = (const float*)d_in[5];
    const unsigned char* mask_left  = (const unsigned char*)d_in[6];
    const unsigned char* mask_right = (const unsigned char*)d_in[7];
    const float* bw    = (const float*)d_in[8];
    const float* wt    = (const float*)d_in[9];
    const float* wh    = (const float*)d_in[10];
    const float* gamma = (const float*)d_in[11];
    const float* beta  = (const float*)d_in[12];
    float* out = (float*)d_out;

    float* ws   = (float*)d_ws;
    float* wcat = ws + WS_WCAT;
    float* hW   = ws + WS_HW;
    float* ctxb = ws + WS_CTX;

    k_prep <<<dim3(288),  dim3(256), 0, stream>>>(head_left, head_right, bw, wt, wh, wcat, hW);
    k_attn <<<dim3(8192), dim3(256), 0, stream>>>(rel_left, tail_left, rel_right, tail_right,
                                                  mask_left, mask_right, hW, ctxb);
    k_outln<<<dim3(512),  dim3(256), 0, stream>>>(ctxb, head_left, head_right, wcat,
                                                  gamma, beta, out);
}